// Round 1
// baseline (1675.492 us; speedup 1.0000x reference)
//
#include <hip/hip_runtime.h>
#include <hip/hip_bf16.h>
#include <stdint.h>

// ---------------------------------------------------------------------------
// Generator_35957466202124: 4x (per-channel dense64 + relu + full-seq cumsum/N)
// + final per-channel dense to 8 logits.  B=4, 65536 pixels, 3 channels, F=64.
//
// R1 design (staged, fp32):
//  - chunk = 64 pixels (192 positions); 1024 chunks/batch; block=256 thr.
//  - per-channel pixel-cumsum + closed-form in-pixel combine (channel-uniform
//    inner loops -> W column cached in 64 VGPRs, x via wave-broadcast float4).
//  - carry folded into bias via dot(carry, Wcol): no offset-add pass.
//  - layer0 = 6KB LUT (din=1, 8 input levels).
//  - y_local updated IN PLACE (reads precede barrier, writes after) -> one
//    201MB buffer; bf16 storage fallback if ws_size too small.
// ---------------------------------------------------------------------------

#define BB   4
#define SP   65536                 // pixels per batch
#define SS   196608                // positions per batch
#define FF   64
#define PCH  64                    // pixels per chunk
#define TCH  (PCH * 3)             // positions per chunk
#define CC   (SP / PCH)            // 1024 chunks per batch
#define NBLK (BB * CC)             // 4096 blocks
#define INVN (1.0f / 196608.0f)

// ---------------- storage adapters (fp32 primary, bf16 fallback) -----------
struct SF32 {
    typedef float T;
    static __device__ __forceinline__ float4 ld4(const T* p) {
        return *reinterpret_cast<const float4*>(p);
    }
    static __device__ __forceinline__ void st(T* p, float v) { *p = v; }
};
struct SBF16 {
    typedef unsigned short T;
    static __device__ __forceinline__ float4 ld4(const T* p) {
        ushort4 u = *reinterpret_cast<const ushort4*>(p);
        float4 r;
        r.x = __uint_as_float((unsigned)u.x << 16);
        r.y = __uint_as_float((unsigned)u.y << 16);
        r.z = __uint_as_float((unsigned)u.z << 16);
        r.w = __uint_as_float((unsigned)u.w << 16);
        return r;
    }
    static __device__ __forceinline__ void st(T* p, float v) {  // RTNE
        unsigned x = __float_as_uint(v);
        unsigned r = (x + 0x7fffu + ((x >> 16) & 1u)) >> 16;
        *p = (unsigned short)r;
    }
};

// ---------------- shared scan + emit tail ----------------------------------
// y[c][p]: relu outputs for this thread's 16 pixels (g-th quarter of chunk).
// Produces: in-chunk flattened inclusive cumsum written to yout, chunk
// aggregate written to A.
template <typename ST>
__device__ __forceinline__ void scan_emit(float (&y)[3][16], int f, int g,
                                          int b, int ci,
                                          typename ST::T* yout, float* A,
                                          float (&seg)[3][4][64])
{
    // thread-local inclusive scan per channel over its 16 pixels
#pragma unroll
    for (int c = 0; c < 3; ++c)
#pragma unroll
        for (int p = 1; p < 16; ++p) y[c][p] += y[c][p - 1];

#pragma unroll
    for (int c = 0; c < 3; ++c) seg[c][g][f] = y[c][15];
    __syncthreads();   // also orders all in-place global READS before WRITES

    float off[3];
#pragma unroll
    for (int c = 0; c < 3; ++c) {
        float o = 0.f;
        for (int g2 = 0; g2 < g; ++g2) o += seg[c][g2][f];  // g wave-uniform
        off[c] = o;
    }
    if (g == 0) {
        float agg = 0.f;
#pragma unroll
        for (int c = 0; c < 3; ++c)
#pragma unroll
            for (int g2 = 0; g2 < 4; ++g2) agg += seg[c][g2][f];
        A[((size_t)b * CC + ci) * FF + f] = agg;
    }

    size_t rowbase = (size_t)b * SS + (size_t)(ci * PCH + g * 16) * 3;
#pragma unroll
    for (int p = 0; p < 16; ++p) {
        float S0 = y[0][p] + off[0];
        float S1 = y[1][p] + off[1];
        float S2 = y[2][p] + off[2];
        float P0 = p ? y[0][p - 1] + off[0] : off[0];  (void)P0;
        float P1 = p ? y[1][p - 1] + off[1] : off[1];
        float P2 = p ? y[2][p - 1] + off[2] : off[2];
        float r0 = S0 + P1 + P2;   // pos (p, c=0)
        float r1 = S0 + S1 + P2;   // pos (p, c=1)
        float r2 = S0 + S1 + S2;   // pos (p, c=2)
        size_t r = rowbase + (size_t)p * 3;
        ST::st(yout + (r + 0) * FF + f, r0);
        ST::st(yout + (r + 1) * FF + f, r1);
        ST::st(yout + (r + 2) * FF + f, r2);
    }
}

// ---------------- layer 0: LUT + scan ---------------------------------------
template <typename ST>
__global__ __launch_bounds__(256)
void l0_kernel(const int* __restrict__ ex, typename ST::T* yout,
               float* __restrict__ A, const float* __restrict__ tab)
{
    __shared__ float seg[3][4][64];
    __shared__ float stab[3 * 8 * 64];
    for (int i = threadIdx.x; i < 1536; i += 256) stab[i] = tab[i];
    __syncthreads();

    int b = blockIdx.x / CC, ci = blockIdx.x % CC;
    int f = threadIdx.x & 63, g = threadIdx.x >> 6;

    float y[3][16];
#pragma unroll
    for (int c = 0; c < 3; ++c)
#pragma unroll
        for (int p = 0; p < 16; ++p) {
            int pix = ci * PCH + g * 16 + p;
            int v = ex[((size_t)b * SP + pix) * 3 + c];
            y[c][p] = stab[(c * 8 + v) * FF + f];
        }
    scan_emit<ST>(y, f, g, b, ci, yout, A, seg);
}

// ---------------- middle layers: dense64 + relu + scan ----------------------
template <typename ST>
__global__ __launch_bounds__(256)
void mid_kernel(const typename ST::T* yin, typename ST::T* yout,
                const float* __restrict__ carry, float* __restrict__ A,
                const float* __restrict__ Wt,     // [3][f][d] this layer
                const float* __restrict__ bias)   // [3][64] this layer
{
    __shared__ float seg[3][4][64];
    int b = blockIdx.x / CC, ci = blockIdx.x % CC;
    int f = threadIdx.x & 63, g = threadIdx.x >> 6;
    const float* cr = carry + ((size_t)b * CC + ci) * FF;

    float y[3][16];
#pragma unroll
    for (int c = 0; c < 3; ++c) {
        float w[64];
        const float* wp = Wt + (size_t)(c * FF + f) * FF;
#pragma unroll
        for (int d4 = 0; d4 < 16; ++d4) {
            float4 v = *reinterpret_cast<const float4*>(wp + d4 * 4);
            w[4 * d4] = v.x; w[4 * d4 + 1] = v.y;
            w[4 * d4 + 2] = v.z; w[4 * d4 + 3] = v.w;
        }
        // carry folded into bias: dot(carry, Wcol)
        float c0 = 0.f, c1 = 0.f, c2 = 0.f, c3 = 0.f;
#pragma unroll
        for (int d4 = 0; d4 < 16; ++d4) {
            float4 v = *reinterpret_cast<const float4*>(cr + d4 * 4);
            c0 += v.x * w[4 * d4];     c1 += v.y * w[4 * d4 + 1];
            c2 += v.z * w[4 * d4 + 2]; c3 += v.w * w[4 * d4 + 3];
        }
        float base = bias[c * FF + f] + INVN * ((c0 + c1) + (c2 + c3));
#pragma unroll
        for (int p = 0; p < 16; ++p) {
            size_t row = (size_t)b * SS + (size_t)(ci * PCH + g * 16 + p) * 3 + c;
            const typename ST::T* xp = yin + row * FF;
            float s0 = 0.f, s1 = 0.f, s2 = 0.f, s3 = 0.f;
#pragma unroll
            for (int d4 = 0; d4 < 16; ++d4) {
                float4 xv = ST::ld4(xp + d4 * 4);   // wave-broadcast load
                s0 += xv.x * w[4 * d4];     s1 += xv.y * w[4 * d4 + 1];
                s2 += xv.z * w[4 * d4 + 2]; s3 += xv.w * w[4 * d4 + 3];
            }
            y[c][p] = fmaxf(base + INVN * ((s0 + s1) + (s2 + s3)), 0.f);
        }
    }
    scan_emit<ST>(y, f, g, b, ci, yout, A, seg);
}

// ---------------- chunk-aggregate exclusive scan ----------------------------
__global__ __launch_bounds__(256)
void scanA(const float* __restrict__ A, float* __restrict__ carry)
{
    __shared__ float seg[4][64];
    int b = blockIdx.x;
    int f = threadIdx.x & 63, g = threadIdx.x >> 6;
    const float* ap = A + (size_t)b * CC * FF;
    float* cp = carry + (size_t)b * CC * FF;
    int j0 = g * (CC / 4), j1 = j0 + (CC / 4);
    float sum = 0.f;
#pragma unroll 8
    for (int j = j0; j < j1; ++j) sum += ap[(size_t)j * FF + f];
    seg[g][f] = sum;
    __syncthreads();
    float run = 0.f;
    for (int g2 = 0; g2 < g; ++g2) run += seg[g2][f];
#pragma unroll 4
    for (int j = j0; j < j1; ++j) {
        cp[(size_t)j * FF + f] = run;
        run += ap[(size_t)j * FF + f];
    }
}

// ---------------- final dense to 8 logits -----------------------------------
template <typename ST>
__global__ __launch_bounds__(192)
void final_kernel(const typename ST::T* __restrict__ yin,
                  const float* __restrict__ carry,
                  const float* __restrict__ Wf,   // [3][8][64]
                  const float* __restrict__ bf,   // [3][8]
                  float* __restrict__ out)
{
    __shared__ __align__(16) float swf[1536];
    __shared__ float scarry[64];
    __shared__ float pcd[24][8];
    __shared__ float scd[24];
    __shared__ float sbf[24];
    int b = blockIdx.x / CC, ci = blockIdx.x % CC;
    int tid = threadIdx.x;

    for (int i = tid; i < 1536; i += 192) swf[i] = Wf[i];
    if (tid < 64) scarry[tid] = carry[((size_t)b * CC + ci) * FF + tid];
    if (tid < 24) sbf[tid] = bf[tid];
    __syncthreads();

    {   // cdot[c][k] = dot(carry, Wf[c][:,k]), parallel over 192 threads
        int pair = tid >> 3, dg = tid & 7;
        float s = 0.f;
#pragma unroll
        for (int dd = 0; dd < 8; ++dd) {
            int d = dg * 8 + dd;
            s += scarry[d] * swf[pair * 64 + d];
        }
        pcd[pair][dg] = s;
    }
    __syncthreads();
    if (tid < 24) {
        float t = 0.f;
#pragma unroll
        for (int j = 0; j < 8; ++j) t += pcd[tid][j];
        scd[tid] = t;
    }
    __syncthreads();

    int c = tid % 3;
    size_t row = (size_t)b * SS + (size_t)ci * TCH + tid;  // one position/thread
    const typename ST::T* xp = yin + row * FF;
    float sk[8];
#pragma unroll
    for (int k = 0; k < 8; ++k) sk[k] = 0.f;
#pragma unroll
    for (int d4 = 0; d4 < 16; ++d4) {
        float4 xv = ST::ld4(xp + d4 * 4);
#pragma unroll
        for (int k = 0; k < 8; ++k) {
            float4 wv = *reinterpret_cast<const float4*>(&swf[(c * 8 + k) * 64 + d4 * 4]);
            sk[k] += xv.x * wv.x + xv.y * wv.y + xv.z * wv.z + xv.w * wv.w;
        }
    }
    float o[8];
#pragma unroll
    for (int k = 0; k < 8; ++k)
        o[k] = sbf[c * 8 + k] + INVN * (scd[c * 8 + k] + sk[k]);
    float4* op = reinterpret_cast<float4*>(out + row * 8);
    op[0] = make_float4(o[0], o[1], o[2], o[3]);
    op[1] = make_float4(o[4], o[5], o[6], o[7]);
}

// ---------------- weight transpose / LUT prep -------------------------------
__global__ __launch_bounds__(256)
void prep(const float* __restrict__ W0, const float* __restrict__ b0,
          const float* __restrict__ Wr, const float* __restrict__ Wfin,
          float* __restrict__ Wt, float* __restrict__ Wf, float* __restrict__ tab)
{
    int i = blockIdx.x * blockDim.x + threadIdx.x;
    int nth = gridDim.x * blockDim.x;
    for (int idx = i; idx < 36864; idx += nth) {      // Wt[l][c][f][d]
        int d = idx & 63, fo = (idx >> 6) & 63, lc = idx >> 12;
        Wt[idx] = Wr[((size_t)(lc * 64 + d)) * 64 + fo];
    }
    for (int idx = i; idx < 1536; idx += nth) {       // Wf[c][k][d]
        int d = idx & 63, k = (idx >> 6) & 7, c2 = idx >> 9;
        Wf[idx] = Wfin[((size_t)(c2 * 64 + d)) * 8 + k];
    }
    for (int idx = i; idx < 1536; idx += nth) {       // tab[c][v][f]
        int fo = idx & 63, v = (idx >> 6) & 7, c2 = idx >> 9;
        float xv = v * 0.25f - 1.0f;
        tab[idx] = fmaxf(W0[c2 * 64 + fo] * xv + b0[c2 * 64 + fo], 0.f);
    }
}

// ---------------- host side --------------------------------------------------
template <typename ST>
static void run_pipe(const int* ex, const float* W0, const float* b0,
                     const float* Wr, const float* br, const float* Wfin,
                     const float* bfin, float* out, char* ws, hipStream_t stream)
{
    typedef typename ST::T T;
    T* Y = (T*)ws;
    size_t ybytes = (size_t)BB * SS * FF * sizeof(T);
    float* A     = (float*)(ws + ybytes);
    float* carry = A + (size_t)BB * CC * FF;
    float* Wt    = carry + (size_t)BB * CC * FF;
    float* Wf    = Wt + 36864;
    float* tab   = Wf + 1536;

    prep<<<64, 256, 0, stream>>>(W0, b0, Wr, Wfin, Wt, Wf, tab);
    l0_kernel<ST><<<NBLK, 256, 0, stream>>>(ex, Y, A, tab);
    scanA<<<BB, 256, 0, stream>>>(A, carry);
    for (int l = 0; l < 3; ++l) {
        mid_kernel<ST><<<NBLK, 256, 0, stream>>>(Y, Y, carry, A,
                                                 Wt + (size_t)l * 12288,
                                                 br + (size_t)l * 192);
        scanA<<<BB, 256, 0, stream>>>(A, carry);
    }
    final_kernel<ST><<<NBLK, 192, 0, stream>>>(Y, carry, Wf, bfin, out);
}

extern "C" void kernel_launch(void* const* d_in, const int* in_sizes, int n_in,
                              void* d_out, int out_size, void* d_ws, size_t ws_size,
                              hipStream_t stream)
{
    const int*   ex   = (const int*)d_in[0];
    const float* W0   = (const float*)d_in[1];
    const float* b0   = (const float*)d_in[2];
    const float* Wr   = (const float*)d_in[3];
    const float* br   = (const float*)d_in[4];
    const float* Wfin = (const float*)d_in[5];
    const float* bfin = (const float*)d_in[6];
    float* out = (float*)d_out;

    size_t nY = (size_t)BB * SS * FF;
    size_t smallBytes = (2 * (size_t)BB * CC * FF + 36864 + 1536 + 1536) * sizeof(float);
    size_t f32Bytes = nY * sizeof(float) + smallBytes;

    if (ws_size >= f32Bytes)
        run_pipe<SF32>(ex, W0, b0, Wr, br, Wfin, bfin, out, (char*)d_ws, stream);
    else
        run_pipe<SBF16>(ex, W0, b0, Wr, br, Wfin, bfin, out, (char*)d_ws, stream);
}

// Round 2
// 414.565 us; speedup vs baseline: 4.0416x; 4.0416x over previous
//
#include <hip/hip_runtime.h>
#include <stdint.h>

// ---------------------------------------------------------------------------
// R2: MFMA-f16 staged pipeline.
//  Y layout: channel-planar f16 [b][c][pix][64]  (pix-major rows, feat contig)
//  per layer: mid_mfma (dense64 via mfma_f32_16x16x32_f16 + fp32 scan + LDS
//  bounce store) -> scanA (chunk-carry scan). carry-dot folded into mid head.
// ---------------------------------------------------------------------------

#define BB   4
#define SP   65536
#define SS   196608
#define CC   1024            // chunks/batch, 64 pixels each
#define NBLK (BB * CC)
#define INVN (1.0f / 196608.0f)

typedef __attribute__((ext_vector_type(8))) _Float16 half8;
typedef __attribute__((ext_vector_type(4))) float    f32x4;

// ---------------- prep: W transposes (f32 + f16) + layer-0 LUT --------------
__global__ __launch_bounds__(256)
void prep(const float* __restrict__ W0, const float* __restrict__ b0,
          const float* __restrict__ Wr, const float* __restrict__ Wfin,
          float* __restrict__ Wt32, _Float16* __restrict__ Wt16,
          float* __restrict__ Wf, float* __restrict__ tab)
{
    int i = blockIdx.x * 256 + threadIdx.x;
    int nth = gridDim.x * 256;
    for (int idx = i; idx < 36864; idx += nth) {     // Wt[l][c][f][d] = Wr[l][c][d][f]
        int d = idx & 63, f = (idx >> 6) & 63, lc = idx >> 12;
        float v = Wr[(size_t)(lc * 64 + d) * 64 + f];
        Wt32[idx] = v;
        Wt16[idx] = (_Float16)v;
    }
    for (int idx = i; idx < 1536; idx += nth) {      // Wf[c][k][d]
        int d = idx & 63, k = (idx >> 6) & 7, c = idx >> 9;
        Wf[idx] = Wfin[(size_t)(c * 64 + d) * 8 + k];
    }
    for (int idx = i; idx < 1536; idx += nth) {      // tab[c][v][f] = relu(W0*x+b0)
        int f = idx & 63, v = (idx >> 6) & 7, c = idx >> 9;
        float xv = v * 0.25f - 1.0f;
        tab[idx] = fmaxf(W0[c * 64 + f] * xv + b0[c * 64 + f], 0.f);
    }
}

// ---------------- layer 0: LUT + local scan + planar f16 store --------------
__global__ __launch_bounds__(256)
void l0_kernel(const int* __restrict__ ex, _Float16* __restrict__ Y,
               float* __restrict__ A, const float* __restrict__ tab)
{
    __shared__ float stab[1536];
    __shared__ float seg[3][4][64];
    int tid = threadIdx.x;
    for (int i = tid; i < 1536; i += 256) stab[i] = tab[i];
    __syncthreads();

    int b = blockIdx.x / CC, ci = blockIdx.x % CC;
    int f = tid & 63, g = tid >> 6;
    int pixbase = ci * 64 + g * 16;

    float y[3][16];
#pragma unroll
    for (int p = 0; p < 16; ++p) {
        const int* ep = ex + ((size_t)b * SP + pixbase + p) * 3;
#pragma unroll
        for (int c = 0; c < 3; ++c) y[c][p] = stab[(c * 8 + ep[c]) * 64 + f];
    }
#pragma unroll
    for (int c = 0; c < 3; ++c)
#pragma unroll
        for (int p = 1; p < 16; ++p) y[c][p] += y[c][p - 1];

#pragma unroll
    for (int c = 0; c < 3; ++c) seg[c][g][f] = y[c][15];
    __syncthreads();

    float off[3];
#pragma unroll
    for (int c = 0; c < 3; ++c) {
        float o = 0.f;
        for (int g2 = 0; g2 < g; ++g2) o += seg[c][g2][f];
        off[c] = o;
    }
    if (g == 0) {
        float agg = 0.f;
#pragma unroll
        for (int c = 0; c < 3; ++c)
#pragma unroll
            for (int g2 = 0; g2 < 4; ++g2) agg += seg[c][g2][f];
        A[((size_t)b * CC + ci) * 64 + f] = agg;
    }

#pragma unroll
    for (int p = 0; p < 16; ++p) {
        float S0 = y[0][p] + off[0], S1 = y[1][p] + off[1], S2 = y[2][p] + off[2];
        float P1 = p ? y[1][p - 1] + off[1] : off[1];
        float P2 = p ? y[2][p - 1] + off[2] : off[2];
        float r0 = S0 + P1 + P2, r1 = S0 + S1 + P2, r2 = S0 + S1 + S2;
        size_t pix = (size_t)pixbase + p;
        Y[((size_t)(b * 3 + 0) * SP + pix) * 64 + f] = (_Float16)r0;
        Y[((size_t)(b * 3 + 1) * SP + pix) * 64 + f] = (_Float16)r1;
        Y[((size_t)(b * 3 + 2) * SP + pix) * 64 + f] = (_Float16)r2;
    }
}

// ---------------- chunk-aggregate exclusive scan (per batch) ----------------
__global__ __launch_bounds__(1024)
void scanA(const float* __restrict__ A, float* __restrict__ carry)
{
    __shared__ float seg[16][65];
    int b = blockIdx.x, tid = threadIdx.x;
    int f = tid & 63, g = tid >> 6;           // g in [0,16)
    const float* ap = A + (size_t)b * CC * 64;
    float* cp = carry + (size_t)b * CC * 64;
    int j0 = g * 64;
    float sum = 0.f;
#pragma unroll 8
    for (int j = 0; j < 64; ++j) sum += ap[(size_t)(j0 + j) * 64 + f];
    seg[g][f] = sum;
    __syncthreads();
    float run = 0.f;
    for (int g2 = 0; g2 < g; ++g2) run += seg[g2][f];
    for (int j = 0; j < 64; ++j) {
        float v = ap[(size_t)(j0 + j) * 64 + f];
        cp[(size_t)(j0 + j) * 64 + f] = run;
        run += v;
    }
}

// ---------------- middle layer: MFMA dense + scan + bounce store ------------
// Yin/Yout alias (in-place; reads complete before writes within block).
__global__ __launch_bounds__(256, 4)
void mid_mfma(const _Float16* Yin, _Float16* Yout,
              const float* __restrict__ carry, float* __restrict__ A,
              const _Float16* __restrict__ W16,   // [3][f][k] f16
              const float* __restrict__ W32,      // [3][f][d] f32
              const float* __restrict__ bias)     // [3][64]
{
    __shared__ float seg[3][1040];                // [3][16 segs][65 pad]
    __shared__ float basearr[3][64];
    __shared__ float tot[3][64];
    __shared__ _Float16 bounce[64 * 72];          // stride 72 f16 (bank spread)

    int b = blockIdx.x / CC, ci = blockIdx.x % CC;
    int tid = threadIdx.x;
    int w = tid >> 6, l = tid & 63;
    int lm = l & 15, lq = l >> 4;
    int p0 = ci * 64 + w * 16;                    // wave's global pixel base

    // head: base[c][f] = bias + INVN*dot(carry, W[:,f]) (overlaps MFMA issue)
    if (tid < 192) {
        int c = tid >> 6, f = tid & 63;
        const float* cr = carry + ((size_t)b * CC + ci) * 64;
        const float* wp = W32 + (size_t)(c * 64 + f) * 64;
        float s0 = 0.f, s1 = 0.f, s2 = 0.f, s3 = 0.f;
#pragma unroll
        for (int d4 = 0; d4 < 16; ++d4) {
            float4 cv = *(const float4*)(cr + d4 * 4);
            float4 wv = *(const float4*)(wp + d4 * 4);
            s0 += cv.x * wv.x; s1 += cv.y * wv.y;
            s2 += cv.z * wv.z; s3 += cv.w * wv.w;
        }
        basearr[c][f] = bias[c * 64 + f] + INVN * ((s0 + s1) + (s2 + s3));
    }

    // MFMA: per channel, per N-tile: acc = Ylocal * W  (K=64 in 2 steps)
    f32x4 acc[3][4];
#pragma unroll
    for (int c = 0; c < 3; ++c) {
        const _Float16* Yc = Yin + ((size_t)(b * 3 + c) * SP) * 64;
        const half8* ap = (const half8*)(Yc + (size_t)(p0 + lm) * 64);
        half8 a0 = ap[lq], a1 = ap[4 + lq];       // k = 0..31 / 32..63 slices
#pragma unroll
        for (int nt = 0; nt < 4; ++nt) {
            const half8* bp = (const half8*)(W16 + (size_t)(c * 64 + nt * 16 + lm) * 64);
            half8 b0 = bp[lq], b1 = bp[4 + lq];
            f32x4 t = {0.f, 0.f, 0.f, 0.f};
            t = __builtin_amdgcn_mfma_f32_16x16x32_f16(a0, b0, t, 0, 0, 0);
            t = __builtin_amdgcn_mfma_f32_16x16x32_f16(a1, b1, t, 0, 0, 0);
            acc[c][nt] = t;
        }
    }
    __syncthreads();   // basearr ready

    // relu + thread-local scan over this lane's 4 pixels (C/D: col=lm, row=lq*4+r)
    float s[3][4][4];
#pragma unroll
    for (int c = 0; c < 3; ++c) {
#pragma unroll
        for (int nt = 0; nt < 4; ++nt) {
            float base = basearr[c][nt * 16 + lm];
            float run = 0.f;
#pragma unroll
            for (int r = 0; r < 4; ++r) {
                float yv = fmaxf(base + INVN * acc[c][nt][r], 0.f);
                run += yv;
                s[c][nt][r] = run;
            }
            seg[c][(w * 4 + lq) * 65 + nt * 16 + lm] = run;   // segment top
        }
    }
    __syncthreads();

    // 16-segment exclusive scan per (c,f); chunk totals
    if (tid < 192) {
        int c = tid >> 6, f = tid & 63;
        float run = 0.f;
#pragma unroll
        for (int sg = 0; sg < 16; ++sg) {
            float v = seg[c][sg * 65 + f];
            seg[c][sg * 65 + f] = run;
            run += v;
        }
        tot[c][f] = run;
    }
    __syncthreads();
    if (tid < 64)
        A[((size_t)b * CC + ci) * 64 + tid] = tot[0][tid] + tot[1][tid] + tot[2][tid];

    float off[3][4];
#pragma unroll
    for (int c = 0; c < 3; ++c)
#pragma unroll
        for (int nt = 0; nt < 4; ++nt)
            off[c][nt] = seg[c][(w * 4 + lq) * 65 + nt * 16 + lm];

    // in-pixel cross-channel combine, bounce -> coalesced planar store
#pragma unroll
    for (int cs = 0; cs < 3; ++cs) {
#pragma unroll
        for (int nt = 0; nt < 4; ++nt) {
#pragma unroll
            for (int r = 0; r < 4; ++r) {
                float S0 = off[0][nt] + s[0][nt][r];
                float S1 = off[1][nt] + s[1][nt][r];
                float S2 = off[2][nt] + s[2][nt][r];
                float P1 = off[1][nt] + (r ? s[1][nt][r - 1] : 0.f);
                float P2 = off[2][nt] + (r ? s[2][nt][r - 1] : 0.f);
                float val = (cs == 0) ? S0 + P1 + P2
                          : (cs == 1) ? S0 + S1 + P2
                                      : S0 + S1 + S2;
                bounce[(w * 16 + lq * 4 + r) * 72 + nt * 16 + lm] = (_Float16)val;
            }
        }
        __syncthreads();
        _Float16* Yo = Yout + ((size_t)(b * 3 + cs) * SP + (size_t)ci * 64) * 64;
#pragma unroll
        for (int it = 0; it < 2; ++it) {
            int i8 = it * 256 + tid;
            int pix = i8 >> 3, f8 = i8 & 7;
            *((half8*)Yo + pix * 8 + f8) = *(const half8*)&bounce[pix * 72 + f8 * 8];
        }
        __syncthreads();
    }
}

// ---------------- final dense to 8 logits -----------------------------------
__global__ __launch_bounds__(192)
void final_kernel(const _Float16* __restrict__ Yin,
                  const float* __restrict__ carry,
                  const float* __restrict__ Wf,   // [3][8][64]
                  const float* __restrict__ bf,   // [3][8]
                  float* __restrict__ out)
{
    __shared__ __align__(16) float swf[1536];
    __shared__ float scarry[64];
    __shared__ float pcd[24][8];
    __shared__ float scd[24];
    __shared__ float sbf[24];
    int b = blockIdx.x / CC, ci = blockIdx.x % CC;
    int tid = threadIdx.x;

    for (int i = tid; i < 1536; i += 192) swf[i] = Wf[i];
    if (tid < 64) scarry[tid] = carry[((size_t)b * CC + ci) * 64 + tid];
    if (tid < 24) sbf[tid] = bf[tid];
    __syncthreads();

    {   // scd[c*8+k] = dot(carry, Wf[c][k][:])
        int pair = tid >> 3, dg = tid & 7;
        float sx = 0.f;
#pragma unroll
        for (int dd = 0; dd < 8; ++dd) {
            int d = dg * 8 + dd;
            sx += scarry[d] * swf[pair * 64 + d];
        }
        pcd[pair][dg] = sx;
    }
    __syncthreads();
    if (tid < 24) {
        float t = 0.f;
#pragma unroll
        for (int j = 0; j < 8; ++j) t += pcd[tid][j];
        scd[tid] = t;
    }
    __syncthreads();

    int c = tid >> 6, j = tid & 63;   // wave per channel, thread per pixel
    const half8* xp = (const half8*)(Yin + ((size_t)(b * 3 + c) * SP + ci * 64 + j) * 64);
    half8 h[8];
#pragma unroll
    for (int i = 0; i < 8; ++i) h[i] = xp[i];
    float sk[8];
#pragma unroll
    for (int k = 0; k < 8; ++k) sk[k] = 0.f;
#pragma unroll
    for (int d4 = 0; d4 < 16; ++d4) {
        half8 hv = h[d4 >> 1];
        int o = (d4 & 1) * 4;
        float x0 = (float)hv[o], x1 = (float)hv[o + 1];
        float x2 = (float)hv[o + 2], x3 = (float)hv[o + 3];
#pragma unroll
        for (int k = 0; k < 8; ++k) {
            float4 wv = *(const float4*)&swf[(c * 8 + k) * 64 + d4 * 4];
            sk[k] += x0 * wv.x + x1 * wv.y + x2 * wv.z + x3 * wv.w;
        }
    }
    size_t pos = (size_t)b * SS + (size_t)(ci * 64 + j) * 3 + c;
    float* op = out + pos * 8;
    float o0[8];
#pragma unroll
    for (int k = 0; k < 8; ++k)
        o0[k] = sbf[c * 8 + k] + INVN * (scd[c * 8 + k] + sk[k]);
    *(float4*)(op + 0) = make_float4(o0[0], o0[1], o0[2], o0[3]);
    *(float4*)(op + 4) = make_float4(o0[4], o0[5], o0[6], o0[7]);
}

// ---------------- host -------------------------------------------------------
extern "C" void kernel_launch(void* const* d_in, const int* in_sizes, int n_in,
                              void* d_out, int out_size, void* d_ws, size_t ws_size,
                              hipStream_t stream)
{
    const int*   ex   = (const int*)d_in[0];
    const float* W0   = (const float*)d_in[1];
    const float* b0   = (const float*)d_in[2];
    const float* Wr   = (const float*)d_in[3];
    const float* br   = (const float*)d_in[4];
    const float* Wfin = (const float*)d_in[5];
    const float* bfin = (const float*)d_in[6];
    float* out = (float*)d_out;

    char* ws = (char*)d_ws;
    _Float16* Y = (_Float16*)ws;                              // 100.7 MB
    size_t off = (size_t)BB * 3 * SP * 64 * sizeof(_Float16);
    float* A     = (float*)(ws + off);  off += (size_t)BB * CC * 64 * 4;
    float* carry = (float*)(ws + off);  off += (size_t)BB * CC * 64 * 4;
    float* Wt32  = (float*)(ws + off);  off += 36864 * 4;
    float* Wf    = (float*)(ws + off);  off += 1536 * 4;
    float* tab   = (float*)(ws + off);  off += 1536 * 4;
    _Float16* Wt16 = (_Float16*)(ws + off); off += 36864 * 2;

    prep<<<64, 256, 0, stream>>>(W0, b0, Wr, Wfin, Wt32, Wt16, Wf, tab);
    l0_kernel<<<NBLK, 256, 0, stream>>>(ex, Y, A, tab);
    scanA<<<BB, 1024, 0, stream>>>(A, carry);
    for (int l = 0; l < 3; ++l) {
        mid_mfma<<<NBLK, 256, 0, stream>>>(Y, Y, carry, A,
                                           Wt16 + (size_t)l * 12288,
                                           Wt32 + (size_t)l * 12288,
                                           br + (size_t)l * 192);
        scanA<<<BB, 1024, 0, stream>>>(A, carry);
    }
    final_kernel<<<NBLK, 192, 0, stream>>>(Y, carry, Wf, bfin, out);
}